// Round 5
// baseline (3433.197 us; speedup 1.0000x reference)
//
#include <hip/hip_runtime.h>
#include <math.h>

// Problem constants
#define B_  4096
#define L_  60
#define I_  13
#define H_  128
#define AHP 136            // h-tile pitch in halfs: 68 dwords/row -> uniform bank spread

typedef _Float16 half8 __attribute__((ext_vector_type(8)));
typedef _Float16 half4v __attribute__((ext_vector_type(4)));
typedef float float4v __attribute__((ext_vector_type(4)));

// ---------------------------------------------------------------------------
// Weight packing: B-fragment order for mfma_f32_16x16x32_f16.
// frag(kt, w4, ct), lane l, elem j ->
//   B[k = kt*32 + (l>>4)*8 + j][n = (ct>>1)*128 + w4*32 + (ct&1)*16 + (l&15)]
// linear e = (((kt*4 + w4)*8 + ct)*64 + l)*8 + j;  src [512][Ksrc] fp32.
// ---------------------------------------------------------------------------
__global__ void pack_kernel(const float* __restrict__ src, _Float16* __restrict__ dst,
                            int Ksrc, int n,
                            const float* __restrict__ bih, const float* __restrict__ bhh,
                            float* __restrict__ bias_out) {
    int g0 = blockIdx.x * blockDim.x + threadIdx.x;
    for (int e = g0; e < n; e += gridDim.x * blockDim.x) {
        int j  = e & 7;
        int l  = (e >> 3) & 63;
        int ct = (e >> 9) & 7;
        int w4 = (e >> 12) & 3;
        int kt = e >> 14;
        int nn = (ct >> 1) * 128 + w4 * 32 + (ct & 1) * 16 + (l & 15);
        int k  = kt * 32 + ((l >> 4) << 3) + j;
        dst[e] = (k < Ksrc) ? (_Float16)src[nn * Ksrc + k] : (_Float16)0.f;
    }
    if (bias_out && g0 < 512) bias_out[g0] = bih[g0] + bhh[g0];
}

__device__ __forceinline__ float sigm(float x) { return 1.f / (1.f + __expf(-x)); }
__device__ __forceinline__ float tanh_f(float x) { return 1.f - 2.f / (__expf(2.f * x) + 1.f); }

// LDS (halfs): WH [0,65536) ; AHm 64 x AHP [65536, 74240) ; AX0 [74240, 76288)
#define SMEM_HALFS 76288
#define SMEM_BYTES (SMEM_HALFS * 2)   // 152576 < 160 KiB

// ---------------------------------------------------------------------------
// Persistent BiLSTM layer, MFMA f16, 512 threads = 8 waves = 2/SIMD.
// Block = 64 batch rows x 1 direction. Wave w: grp = w>>2 picks the 32-row
// half; w4 = w&3 owns n-cols [w4*32,+32) x 4 gates (ct 0..7), rt = 0,1.
// W_hh pack LDS-resident (shared by both grps); W_ih pack streamed from L2
// (same addresses every step -> L2-resident). 2 barriers/step.
// C/D frag: row=(lane>>4)*4+reg, col=lane&15. A/B frag: dim16=lane&15,
// k=(lane>>4)*8+j.  (Validated in R3: absmax 7.8e-3.)
// ---------------------------------------------------------------------------
template <int XT, int IS_L0>
__global__ __launch_bounds__(512, 2)
void lstm_mfma(const float* __restrict__ x0, const _Float16* __restrict__ yin,
               const _Float16* __restrict__ px_f, const _Float16* __restrict__ ph_f,
               const _Float16* __restrict__ px_b, const _Float16* __restrict__ ph_b,
               const float* __restrict__ bias_f, const float* __restrict__ bias_b,
               _Float16* __restrict__ yout)
{
    extern __shared__ _Float16 sm[];
    _Float16* WH  = sm;                    // 65536 halfs (128 KB)
    _Float16* AHm = sm + 65536;            // 64 x AHP
    _Float16* AX0 = sm + 74240;            // 2048 halfs (L0 staging)

    const int tid  = threadIdx.x;
    const int lane = tid & 63;
    const int w    = tid >> 6;      // 0..7
    const int w4   = w & 3;
    const int grp  = w >> 2;        // 0/1: which 32-row half
    const int dir  = blockIdx.x & 1;
    const int rb   = (blockIdx.x >> 1) * 64;
    const int m    = lane & 15;
    const int q    = lane >> 4;

    const _Float16* __restrict__ px   = dir ? px_b : px_f;
    const _Float16* __restrict__ ph   = dir ? ph_b : ph_f;
    const float*    __restrict__ bias = dir ? bias_b : bias_f;
    const _Float16* __restrict__ pWl  = px + w4 * 4096 + lane * 8;
    const _Float16* __restrict__ WHl  = WH + w4 * 4096 + lane * 8;

    // Load W_hh pack into LDS (8192 half8), zero h-tile.
    {
        const half8* s8 = (const half8*)ph;
        half8* d8 = (half8*)WH;
        for (int i = tid; i < 8192; i += 512) d8[i] = s8[i];
    }
    for (int i = tid; i < 64 * AHP; i += 512) AHm[i] = (_Float16)0.f;

    float bv[8];
#pragma unroll
    for (int ct = 0; ct < 8; ++ct)
        bv[ct] = bias[(ct >> 1) * 128 + w4 * 32 + (ct & 1) * 16 + m];

    float cst[2][2][4];
#pragma unroll
    for (int rt = 0; rt < 2; ++rt)
#pragma unroll
        for (int u = 0; u < 2; ++u)
#pragma unroll
            for (int r = 0; r < 4; ++r) cst[rt][u][r] = 0.f;

    for (int s = 0; s < L_; ++s) {
        const int t = dir ? (L_ - 1 - s) : s;

        if (IS_L0) {
            // Stage x_t (64 rows) into A-frag order: seg = e>>9 is a 16-row
            // tile; row = seg*16 + ((e>>3)&15), k = ((e>>6)&... decomposed:
            const int e   = tid * 4;
            const int j0  = e & 7;
            const int ln  = (e >> 3) & 63;
            const int seg = e >> 9;
            const int row = seg * 16 + (ln & 15);
            const int kb  = ((ln >> 4) << 3) + j0;
            const float* xr = x0 + (size_t)(rb + row) * (L_ * I_) + t * I_;
            half4v tmp;
#pragma unroll
            for (int jj = 0; jj < 4; ++jj) {
                int k = kb + jj;
                tmp[jj] = (k < I_) ? (_Float16)xr[k] : (_Float16)0.f;
            }
            ((half4v*)AX0)[tid] = tmp;
        }

        __syncthreads();   // (A) h(t-1) + AX0 + WH visible

        float4v acc[2][8];
#pragma unroll
        for (int rt = 0; rt < 2; ++rt)
#pragma unroll
            for (int ct = 0; ct < 8; ++ct) {
                float b = bv[ct];
                acc[rt][ct] = (float4v){b, b, b, b};
            }

        // ---- x-part: B streamed from global pack, A from global yin / AX0 ----
        if (IS_L0) {
            half8 a0 = *(const half8*)(AX0 + grp * 1024 + lane * 8);
            half8 a1 = *(const half8*)(AX0 + grp * 1024 + 512 + lane * 8);
#pragma unroll
            for (int ct = 0; ct < 8; ++ct) {
                half8 b = *(const half8*)(pWl + ct * 512);
                acc[0][ct] = __builtin_amdgcn_mfma_f32_16x16x32_f16(a0, b, acc[0][ct], 0, 0, 0);
                acc[1][ct] = __builtin_amdgcn_mfma_f32_16x16x32_f16(a1, b, acc[1][ct], 0, 0, 0);
            }
        } else {
            const _Float16* abase = yin + (size_t)(rb + grp * 32 + m) * 15360 + t * 256 + q * 8;
            half8 aC0, aC1, bC[8], aN0, aN1, bN[8];
            aC0 = *(const half8*)(abase);
            aC1 = *(const half8*)(abase + 16 * 15360);
#pragma unroll
            for (int ct = 0; ct < 8; ++ct) bC[ct] = *(const half8*)(pWl + ct * 512);
#pragma unroll
            for (int kt = 0; kt < XT; ++kt) {
                if (kt + 1 < XT) {
                    aN0 = *(const half8*)(abase + (kt + 1) * 32);
                    aN1 = *(const half8*)(abase + 16 * 15360 + (kt + 1) * 32);
#pragma unroll
                    for (int ct = 0; ct < 8; ++ct)
                        bN[ct] = *(const half8*)(pWl + (kt + 1) * 16384 + ct * 512);
                }
#pragma unroll
                for (int ct = 0; ct < 8; ++ct) {
                    acc[0][ct] = __builtin_amdgcn_mfma_f32_16x16x32_f16(aC0, bC[ct], acc[0][ct], 0, 0, 0);
                    acc[1][ct] = __builtin_amdgcn_mfma_f32_16x16x32_f16(aC1, bC[ct], acc[1][ct], 0, 0, 0);
                }
                aC0 = aN0; aC1 = aN1;
#pragma unroll
                for (int ct = 0; ct < 8; ++ct) bC[ct] = bN[ct];
            }
        }

        // ---- h-part: A from LDS h-tile (own grp rows), B from LDS W_hh ----
#pragma unroll
        for (int kh = 0; kh < 4; ++kh) {
            half8 a0 = *(const half8*)(AHm + (grp * 32 + m) * AHP + kh * 32 + q * 8);
            half8 a1 = *(const half8*)(AHm + (grp * 32 + 16 + m) * AHP + kh * 32 + q * 8);
#pragma unroll
            for (int ct = 0; ct < 8; ++ct) {
                half8 b = *(const half8*)(WHl + kh * 16384 + ct * 512);
                acc[0][ct] = __builtin_amdgcn_mfma_f32_16x16x32_f16(a0, b, acc[0][ct], 0, 0, 0);
                acc[1][ct] = __builtin_amdgcn_mfma_f32_16x16x32_f16(a1, b, acc[1][ct], 0, 0, 0);
            }
        }

        __syncthreads();   // (B) all h-tile reads done -> safe to overwrite h

        // ---- pointwise LSTM cell (i,f,g,o) in registers, 16 elems/thread ----
#pragma unroll
        for (int rt = 0; rt < 2; ++rt)
#pragma unroll
            for (int u = 0; u < 2; ++u)
#pragma unroll
                for (int r = 0; r < 4; ++r) {
                    const float gi = acc[rt][0 + u][r];
                    const float gf = acc[rt][2 + u][r];
                    const float gg = acc[rt][4 + u][r];
                    const float go = acc[rt][6 + u][r];
                    const float cc = sigm(gf) * cst[rt][u][r] + sigm(gi) * tanh_f(gg);
                    cst[rt][u][r] = cc;
                    const float hh = sigm(go) * tanh_f(cc);
                    const int row = grp * 32 + rt * 16 + q * 4 + r;
                    const int j   = w4 * 32 + u * 16 + m;
                    AHm[row * AHP + j] = (_Float16)hh;
                    yout[(size_t)(rb + row) * 15360 + t * 256 + dir * H_ + j] = (_Float16)hh;
                }
    }
}

// ---------------------------------------------------------------------------
// Final: out[b][o] = b_out[o] + sum relu(y3[b][:]) * w_out[o][:]
// ---------------------------------------------------------------------------
__global__ __launch_bounds__(256)
void final_kernel(const _Float16* __restrict__ y, const float* __restrict__ wout,
                  const float* __restrict__ bout, float* __restrict__ outp, int nrows) {
    const int wid  = (blockIdx.x * blockDim.x + threadIdx.x) >> 6;
    const int lane = threadIdx.x & 63;
    if (wid >= nrows) return;
    const half8*  __restrict__ y8 = (const half8*)(y + (size_t)wid * 15360);
    const float4* __restrict__ w4 = (const float4*)wout;   // [2][3840]
    float s0 = 0.f, s1 = 0.f;
#pragma unroll 2
    for (int it = 0; it < 30; ++it) {
        const int idx = it * 64 + lane;
        half8 h = y8[idx];
        float v[8];
#pragma unroll
        for (int e = 0; e < 8; ++e) v[e] = fmaxf((float)h[e], 0.f);
        const float4 a0 = w4[idx * 2], a1 = w4[idx * 2 + 1];
        const float4 b0 = w4[3840 + idx * 2], b1 = w4[3840 + idx * 2 + 1];
        s0 += v[0] * a0.x + v[1] * a0.y + v[2] * a0.z + v[3] * a0.w
            + v[4] * a1.x + v[5] * a1.y + v[6] * a1.z + v[7] * a1.w;
        s1 += v[0] * b0.x + v[1] * b0.y + v[2] * b0.z + v[3] * b0.w
            + v[4] * b1.x + v[5] * b1.y + v[6] * b1.z + v[7] * b1.w;
    }
#pragma unroll
    for (int off = 32; off > 0; off >>= 1) {
        s0 += __shfl_down(s0, off);
        s1 += __shfl_down(s1, off);
    }
    if (lane == 0) {
        outp[wid * 2 + 0] = s0 + bout[0];
        outp[wid * 2 + 1] = s1 + bout[1];
    }
}

// ---------------------------------------------------------------------------
extern "C" void kernel_launch(void* const* d_in, const int* in_sizes, int n_in,
                              void* d_out, int out_size, void* d_ws, size_t ws_size,
                              hipStream_t stream) {
    const float* x = (const float*)d_in[0];
    auto W = [&](int l, int d, int which) { return (const float*)d_in[1 + l * 8 + d * 4 + which]; };
    const float* w_out = (const float*)d_in[25];
    const float* b_out = (const float*)d_in[26];

    // Workspace: packs (halfs) -> fp32 bias -> fp16 y ping-pong buffers.
    _Float16* wsH = (_Float16*)d_ws;
    const size_t px0f = 0,       ph0f = 16384;
    const size_t px0b = 81920,   ph0b = 98304;
    const size_t px1f = 163840,  ph1f = 294912;
    const size_t px1b = 360448,  ph1b = 491520;
    const size_t px2f = 557056,  ph2f = 688128;
    const size_t px2b = 753664,  ph2b = 884736;
    const size_t packs_end = 950272;
    float* bias = (float*)(wsH + packs_end);      // 6*512 fp32
    const size_t head_bytes = packs_end * 2 + 4096 * 4;
    _Float16* y0 = (_Float16*)((char*)d_ws + head_bytes);

    hipFuncSetAttribute((const void*)lstm_mfma<1, 1>, hipFuncAttributeMaxDynamicSharedMemorySize, SMEM_BYTES);
    hipFuncSetAttribute((const void*)lstm_mfma<8, 0>, hipFuncAttributeMaxDynamicSharedMemorySize, SMEM_BYTES);

    // ---- weight packing (+ bias combine on the px launches) ----
    pack_kernel<<<64, 256, 0, stream>>>(W(0,0,0), wsH + px0f, I_,  16384,  W(0,0,2), W(0,0,3), bias + 0);
    pack_kernel<<<256,256, 0, stream>>>(W(0,0,1), wsH + ph0f, H_,  65536,  nullptr, nullptr, nullptr);
    pack_kernel<<<64, 256, 0, stream>>>(W(0,1,0), wsH + px0b, I_,  16384,  W(0,1,2), W(0,1,3), bias + 512);
    pack_kernel<<<256,256, 0, stream>>>(W(0,1,1), wsH + ph0b, H_,  65536,  nullptr, nullptr, nullptr);
    pack_kernel<<<512,256, 0, stream>>>(W(1,0,0), wsH + px1f, 256, 131072, W(1,0,2), W(1,0,3), bias + 1024);
    pack_kernel<<<256,256, 0, stream>>>(W(1,0,1), wsH + ph1f, H_,  65536,  nullptr, nullptr, nullptr);
    pack_kernel<<<512,256, 0, stream>>>(W(1,1,0), wsH + px1b, 256, 131072, W(1,1,2), W(1,1,3), bias + 1536);
    pack_kernel<<<256,256, 0, stream>>>(W(1,1,1), wsH + ph1b, H_,  65536,  nullptr, nullptr, nullptr);
    pack_kernel<<<512,256, 0, stream>>>(W(2,0,0), wsH + px2f, 256, 131072, W(2,0,2), W(2,0,3), bias + 2048);
    pack_kernel<<<256,256, 0, stream>>>(W(2,0,1), wsH + ph2f, H_,  65536,  nullptr, nullptr, nullptr);
    pack_kernel<<<512,256, 0, stream>>>(W(2,1,0), wsH + px2b, 256, 131072, W(2,1,2), W(2,1,3), bias + 2560);
    pack_kernel<<<256,256, 0, stream>>>(W(2,1,1), wsH + ph2b, H_,  65536,  nullptr, nullptr, nullptr);

    // ---- pick batch chunking so 2 fp16 y-buffers fit in remaining ws ----
    const size_t avail_halfs = (ws_size > head_bytes) ? (ws_size - head_bytes) / 2 : 0;
    int chunks = 1;
    while (chunks < 64 && (size_t)2 * (B_ / chunks) * 15360 > avail_halfs) chunks *= 2;
    const int CB = B_ / chunks;              // multiple of 64

    _Float16* yA = y0;
    _Float16* yB = y0 + (size_t)CB * 15360;

    for (int c = 0; c < chunks; ++c) {
        const float* xc = x + (size_t)c * CB * (L_ * I_);
        float* outc = (float*)d_out + (size_t)c * CB * 2;
        lstm_mfma<1, 1><<<CB / 32, 512, SMEM_BYTES, stream>>>(
            xc, nullptr, wsH + px0f, wsH + ph0f, wsH + px0b, wsH + ph0b, bias + 0, bias + 512, yA);
        lstm_mfma<8, 0><<<CB / 32, 512, SMEM_BYTES, stream>>>(
            nullptr, yA, wsH + px1f, wsH + ph1f, wsH + px1b, wsH + ph1b, bias + 1024, bias + 1536, yB);
        lstm_mfma<8, 0><<<CB / 32, 512, SMEM_BYTES, stream>>>(
            nullptr, yB, wsH + px2f, wsH + ph2f, wsH + px2b, wsH + ph2b, bias + 2048, bias + 2560, yA);
        final_kernel<<<(CB + 3) / 4, 256, 0, stream>>>(yA, w_out, b_out, outc, CB);
    }
}

// Round 6
// 1198.081 us; speedup vs baseline: 2.8656x; 2.8656x over previous
//
#include <hip/hip_runtime.h>
#include <math.h>

// Problem constants
#define B_  4096
#define L_  60
#define I_  13
#define H_  128
#define AHP 136            // h-tile pitch in halfs (272B rows: 16B-aligned, odd 16B-groups)

typedef _Float16 half8 __attribute__((ext_vector_type(8)));
typedef _Float16 half4v __attribute__((ext_vector_type(4)));
typedef float float4v __attribute__((ext_vector_type(4)));

// ---------------------------------------------------------------------------
// Weight packing: B-fragment order for mfma_f32_16x16x32_f16.
// frag(kt, w4, ct), lane l, elem j ->
//   B[k = kt*32 + (l>>4)*8 + j][n = (ct>>1)*128 + w4*32 + (ct&1)*16 + (l&15)]
// linear e = (((kt*4 + w4)*8 + ct)*64 + l)*8 + j;  src [512][Ksrc] fp32.
// (Validated R3: absmax 7.8e-3.)
// ---------------------------------------------------------------------------
__global__ void pack_kernel(const float* __restrict__ src, _Float16* __restrict__ dst,
                            int Ksrc, int n,
                            const float* __restrict__ bih, const float* __restrict__ bhh,
                            float* __restrict__ bias_out) {
    int g0 = blockIdx.x * blockDim.x + threadIdx.x;
    for (int e = g0; e < n; e += gridDim.x * blockDim.x) {
        int j  = e & 7;
        int l  = (e >> 3) & 63;
        int ct = (e >> 9) & 7;
        int w4 = (e >> 12) & 3;
        int kt = e >> 14;
        int nn = (ct >> 1) * 128 + w4 * 32 + (ct & 1) * 16 + (l & 15);
        int k  = kt * 32 + ((l >> 4) << 3) + j;
        dst[e] = (k < Ksrc) ? (_Float16)src[nn * Ksrc + k] : (_Float16)0.f;
    }
    if (bias_out && g0 < 512) bias_out[g0] = bih[g0] + bhh[g0];
}

__device__ __forceinline__ float sigm(float x) { return 1.f / (1.f + __expf(-x)); }
__device__ __forceinline__ float tanh_f(float x) { return 1.f - 2.f / (__expf(2.f * x) + 1.f); }

// LDS (halfs): WH [0,65536) ; AHm 32 x AHP [65536, 69888) ; AX0 [69888, 70912)
#define SMEM_HALFS 70912
#define SMEM_BYTES (SMEM_HALFS * 2)   // 141824 -> 1 block/CU, 8 waves = 2/SIMD

// ---------------------------------------------------------------------------
// Persistent BiLSTM layer, MFMA f16. R3 cache structure (256 blocks, 32 rows,
// W_hh LDS-resident, W_ih streamed 256 KB/step/CU) + ct-split occupancy fix:
// 512 threads = 8 waves = 2/SIMD. Wave (w4 = w&3, u = w>>2): w4 owns n-cols
// [w4*32,+32), u picks the 16-col half; wave computes real ct = tq*2+u for
// tq = 0..3 (all 4 gates of its 16 cols) -> complete k-sums, no exchange.
// Per-CU B-fragment traffic identical to R3 (8x4 = 4x8 ct-loads).
// C/D frag: row=(lane>>4)*4+reg, col=lane&15. A/B frag: dim16=lane&15,
// k=(lane>>4)*8+j.
// ---------------------------------------------------------------------------
template <int XT, int IS_L0>
__global__ __launch_bounds__(512, 2)
void lstm_mfma(const float* __restrict__ x0, const _Float16* __restrict__ yin,
               const _Float16* __restrict__ px_f, const _Float16* __restrict__ ph_f,
               const _Float16* __restrict__ px_b, const _Float16* __restrict__ ph_b,
               const float* __restrict__ bias_f, const float* __restrict__ bias_b,
               _Float16* __restrict__ yout)
{
    extern __shared__ _Float16 sm[];
    _Float16* WH  = sm;                    // 65536 halfs (128 KB)
    _Float16* AHm = sm + 65536;            // 32 x AHP
    _Float16* AX0 = sm + 69888;            // 1024 halfs (L0 staging)

    const int tid  = threadIdx.x;
    const int lane = tid & 63;
    const int w    = tid >> 6;      // 0..7
    const int w4   = w & 3;
    const int u    = w >> 2;        // 0/1: 16-col half within the 32-col block
    const int dir  = blockIdx.x & 1;
    const int rb   = (blockIdx.x >> 1) * 32;
    const int m    = lane & 15;
    const int q    = lane >> 4;

    const _Float16* __restrict__ px   = dir ? px_b : px_f;
    const _Float16* __restrict__ ph   = dir ? ph_b : ph_f;
    const float*    __restrict__ bias = dir ? bias_b : bias_f;
    // Fragment base for this wave: pack offset w4*4096 + lane*8; per-kt
    // stride 16384; per-real-ct stride 512 with real ct = tq*2 + u.
    const _Float16* __restrict__ pWl  = px + w4 * 4096 + u * 512 + lane * 8;
    const _Float16* __restrict__ WHl  = WH + w4 * 4096 + u * 512 + lane * 8;

    // Load W_hh pack into LDS (8192 half8), zero h-tile.
    {
        const half8* s8 = (const half8*)ph;
        half8* d8 = (half8*)WH;
        for (int i = tid; i < 8192; i += 512) d8[i] = s8[i];
    }
    for (int i = tid; i < 32 * AHP; i += 512) AHm[i] = (_Float16)0.f;

    float bv[4];
#pragma unroll
    for (int tq = 0; tq < 4; ++tq)
        bv[tq] = bias[tq * 128 + w4 * 32 + u * 16 + m];

    float cst[2][4];
#pragma unroll
    for (int rt = 0; rt < 2; ++rt)
#pragma unroll
        for (int r = 0; r < 4; ++r) cst[rt][r] = 0.f;

    for (int s = 0; s < L_; ++s) {
        const int t = dir ? (L_ - 1 - s) : s;

        if (IS_L0 && tid < 256) {
            // Stage x_t into A-frag order (1024 halfs, zero-pad k>=13).
            const int e  = tid * 4;
            const int j0 = e & 7;
            const int ln = (e >> 3) & 63;
            const int rt = e >> 9;
            const int row = rt * 16 + (ln & 15);
            const int kb  = ((ln >> 4) << 3) + j0;
            const float* xr = x0 + (size_t)(rb + row) * (L_ * I_) + t * I_;
            half4v tmp;
#pragma unroll
            for (int jj = 0; jj < 4; ++jj) {
                int k = kb + jj;
                tmp[jj] = (k < I_) ? (_Float16)xr[k] : (_Float16)0.f;
            }
            ((half4v*)AX0)[tid] = tmp;
        }

        __syncthreads();   // (A) h(t-1) + AX0 + WH visible

        float4v acc[2][4];
#pragma unroll
        for (int rt = 0; rt < 2; ++rt)
#pragma unroll
            for (int tq = 0; tq < 4; ++tq) {
                float b = bv[tq];
                acc[rt][tq] = (float4v){b, b, b, b};
            }

        // ---- x-part: B streamed from global pack, A from global yin / AX0 ----
        if (IS_L0) {
            half8 a0 = *(const half8*)(AX0 + lane * 8);
            half8 a1 = *(const half8*)(AX0 + 512 + lane * 8);
#pragma unroll
            for (int tq = 0; tq < 4; ++tq) {
                half8 b = *(const half8*)(pWl + tq * 1024);
                acc[0][tq] = __builtin_amdgcn_mfma_f32_16x16x32_f16(a0, b, acc[0][tq], 0, 0, 0);
                acc[1][tq] = __builtin_amdgcn_mfma_f32_16x16x32_f16(a1, b, acc[1][tq], 0, 0, 0);
            }
        } else {
            const _Float16* abase = yin + (size_t)(rb + m) * 15360 + t * 256 + q * 8;
            half8 aC0, aC1, bC[4], aN0, aN1, bN[4];
            aC0 = *(const half8*)(abase);
            aC1 = *(const half8*)(abase + 16 * 15360);
#pragma unroll
            for (int tq = 0; tq < 4; ++tq) bC[tq] = *(const half8*)(pWl + tq * 1024);
#pragma unroll
            for (int kt = 0; kt < XT; ++kt) {
                if (kt + 1 < XT) {
                    aN0 = *(const half8*)(abase + (kt + 1) * 32);
                    aN1 = *(const half8*)(abase + 16 * 15360 + (kt + 1) * 32);
#pragma unroll
                    for (int tq = 0; tq < 4; ++tq)
                        bN[tq] = *(const half8*)(pWl + (kt + 1) * 16384 + tq * 1024);
                }
#pragma unroll
                for (int tq = 0; tq < 4; ++tq) {
                    acc[0][tq] = __builtin_amdgcn_mfma_f32_16x16x32_f16(aC0, bC[tq], acc[0][tq], 0, 0, 0);
                    acc[1][tq] = __builtin_amdgcn_mfma_f32_16x16x32_f16(aC1, bC[tq], acc[1][tq], 0, 0, 0);
                }
                aC0 = aN0; aC1 = aN1;
#pragma unroll
                for (int tq = 0; tq < 4; ++tq) bC[tq] = bN[tq];
            }
        }

        // ---- h-part: A from LDS h-tile, B from LDS W_hh pack ----
#pragma unroll
        for (int kh = 0; kh < 4; ++kh) {
            half8 a0 = *(const half8*)(AHm + m * AHP + kh * 32 + q * 8);
            half8 a1 = *(const half8*)(AHm + (16 + m) * AHP + kh * 32 + q * 8);
#pragma unroll
            for (int tq = 0; tq < 4; ++tq) {
                half8 b = *(const half8*)(WHl + kh * 16384 + tq * 1024);
                acc[0][tq] = __builtin_amdgcn_mfma_f32_16x16x32_f16(a0, b, acc[0][tq], 0, 0, 0);
                acc[1][tq] = __builtin_amdgcn_mfma_f32_16x16x32_f16(a1, b, acc[1][tq], 0, 0, 0);
            }
        }

        __syncthreads();   // (B) all h-tile reads done -> safe to overwrite h

        // ---- pointwise LSTM cell (i,f,g,o), 8 elems/thread ----
#pragma unroll
        for (int rt = 0; rt < 2; ++rt)
#pragma unroll
            for (int r = 0; r < 4; ++r) {
                const float gi = acc[rt][0][r];
                const float gf = acc[rt][1][r];
                const float gg = acc[rt][2][r];
                const float go = acc[rt][3][r];
                const float cc = sigm(gf) * cst[rt][r] + sigm(gi) * tanh_f(gg);
                cst[rt][r] = cc;
                const float hh = sigm(go) * tanh_f(cc);
                const int row = rt * 16 + q * 4 + r;
                const int j   = w4 * 32 + u * 16 + m;
                AHm[row * AHP + j] = (_Float16)hh;
                yout[(size_t)(rb + row) * 15360 + t * 256 + dir * H_ + j] = (_Float16)hh;
            }
    }
}

// ---------------------------------------------------------------------------
// Final: out[b][o] = b_out[o] + sum relu(y3[b][:]) * w_out[o][:]
// ---------------------------------------------------------------------------
__global__ __launch_bounds__(256)
void final_kernel(const _Float16* __restrict__ y, const float* __restrict__ wout,
                  const float* __restrict__ bout, float* __restrict__ outp, int nrows) {
    const int wid  = (blockIdx.x * blockDim.x + threadIdx.x) >> 6;
    const int lane = threadIdx.x & 63;
    if (wid >= nrows) return;
    const half8*  __restrict__ y8 = (const half8*)(y + (size_t)wid * 15360);
    const float4* __restrict__ w4 = (const float4*)wout;   // [2][3840]
    float s0 = 0.f, s1 = 0.f;
#pragma unroll 2
    for (int it = 0; it < 30; ++it) {
        const int idx = it * 64 + lane;
        half8 h = y8[idx];
        float v[8];
#pragma unroll
        for (int e = 0; e < 8; ++e) v[e] = fmaxf((float)h[e], 0.f);
        const float4 a0 = w4[idx * 2], a1 = w4[idx * 2 + 1];
        const float4 b0 = w4[3840 + idx * 2], b1 = w4[3840 + idx * 2 + 1];
        s0 += v[0] * a0.x + v[1] * a0.y + v[2] * a0.z + v[3] * a0.w
            + v[4] * a1.x + v[5] * a1.y + v[6] * a1.z + v[7] * a1.w;
        s1 += v[0] * b0.x + v[1] * b0.y + v[2] * b0.z + v[3] * b0.w
            + v[4] * b1.x + v[5] * b1.y + v[6] * b1.z + v[7] * b1.w;
    }
#pragma unroll
    for (int off = 32; off > 0; off >>= 1) {
        s0 += __shfl_down(s0, off);
        s1 += __shfl_down(s1, off);
    }
    if (lane == 0) {
        outp[wid * 2 + 0] = s0 + bout[0];
        outp[wid * 2 + 1] = s1 + bout[1];
    }
}

// ---------------------------------------------------------------------------
extern "C" void kernel_launch(void* const* d_in, const int* in_sizes, int n_in,
                              void* d_out, int out_size, void* d_ws, size_t ws_size,
                              hipStream_t stream) {
    const float* x = (const float*)d_in[0];
    auto W = [&](int l, int d, int which) { return (const float*)d_in[1 + l * 8 + d * 4 + which]; };
    const float* w_out = (const float*)d_in[25];
    const float* b_out = (const float*)d_in[26];

    // Workspace: packs (halfs) -> fp32 bias -> fp16 y ping-pong buffers.
    _Float16* wsH = (_Float16*)d_ws;
    const size_t px0f = 0,       ph0f = 16384;
    const size_t px0b = 81920,   ph0b = 98304;
    const size_t px1f = 163840,  ph1f = 294912;
    const size_t px1b = 360448,  ph1b = 491520;
    const size_t px2f = 557056,  ph2f = 688128;
    const size_t px2b = 753664,  ph2b = 884736;
    const size_t packs_end = 950272;
    float* bias = (float*)(wsH + packs_end);      // 6*512 fp32
    const size_t head_bytes = packs_end * 2 + 4096 * 4;
    _Float16* y0 = (_Float16*)((char*)d_ws + head_bytes);

    hipFuncSetAttribute((const void*)lstm_mfma<1, 1>, hipFuncAttributeMaxDynamicSharedMemorySize, SMEM_BYTES);
    hipFuncSetAttribute((const void*)lstm_mfma<8, 0>, hipFuncAttributeMaxDynamicSharedMemorySize, SMEM_BYTES);

    // ---- weight packing (+ bias combine on the px launches) ----
    pack_kernel<<<64, 256, 0, stream>>>(W(0,0,0), wsH + px0f, I_,  16384,  W(0,0,2), W(0,0,3), bias + 0);
    pack_kernel<<<256,256, 0, stream>>>(W(0,0,1), wsH + ph0f, H_,  65536,  nullptr, nullptr, nullptr);
    pack_kernel<<<64, 256, 0, stream>>>(W(0,1,0), wsH + px0b, I_,  16384,  W(0,1,2), W(0,1,3), bias + 512);
    pack_kernel<<<256,256, 0, stream>>>(W(0,1,1), wsH + ph0b, H_,  65536,  nullptr, nullptr, nullptr);
    pack_kernel<<<512,256, 0, stream>>>(W(1,0,0), wsH + px1f, 256, 131072, W(1,0,2), W(1,0,3), bias + 1024);
    pack_kernel<<<256,256, 0, stream>>>(W(1,0,1), wsH + ph1f, H_,  65536,  nullptr, nullptr, nullptr);
    pack_kernel<<<512,256, 0, stream>>>(W(1,1,0), wsH + px1b, 256, 131072, W(1,1,2), W(1,1,3), bias + 1536);
    pack_kernel<<<256,256, 0, stream>>>(W(1,1,1), wsH + ph1b, H_,  65536,  nullptr, nullptr, nullptr);
    pack_kernel<<<512,256, 0, stream>>>(W(2,0,0), wsH + px2f, 256, 131072, W(2,0,2), W(2,0,3), bias + 2048);
    pack_kernel<<<256,256, 0, stream>>>(W(2,0,1), wsH + ph2f, H_,  65536,  nullptr, nullptr, nullptr);
    pack_kernel<<<512,256, 0, stream>>>(W(2,1,0), wsH + px2b, 256, 131072, W(2,1,2), W(2,1,3), bias + 2560);
    pack_kernel<<<256,256, 0, stream>>>(W(2,1,1), wsH + ph2b, H_,  65536,  nullptr, nullptr, nullptr);

    // ---- pick batch chunking so 2 fp16 y-buffers fit in remaining ws ----
    const size_t avail_halfs = (ws_size > head_bytes) ? (ws_size - head_bytes) / 2 : 0;
    int chunks = 1;
    while (chunks < 128 && (size_t)2 * (B_ / chunks) * 15360 > avail_halfs) chunks *= 2;
    const int CB = B_ / chunks;              // multiple of 32

    _Float16* yA = y0;
    _Float16* yB = y0 + (size_t)CB * 15360;

    for (int c = 0; c < chunks; ++c) {
        const float* xc = x + (size_t)c * CB * (L_ * I_);
        float* outc = (float*)d_out + (size_t)c * CB * 2;
        lstm_mfma<1, 1><<<2 * CB / 32, 512, SMEM_BYTES, stream>>>(
            xc, nullptr, wsH + px0f, wsH + ph0f, wsH + px0b, wsH + ph0b, bias + 0, bias + 512, yA);
        lstm_mfma<8, 0><<<2 * CB / 32, 512, SMEM_BYTES, stream>>>(
            nullptr, yA, wsH + px1f, wsH + ph1f, wsH + px1b, wsH + ph1b, bias + 1024, bias + 1536, yB);
        lstm_mfma<8, 0><<<2 * CB / 32, 512, SMEM_BYTES, stream>>>(
            nullptr, yB, wsH + px2f, wsH + ph2f, wsH + px2b, wsH + ph2b, bias + 2048, bias + 2560, yA);
        final_kernel<<<(CB + 3) / 4, 256, 0, stream>>>(yA, w_out, b_out, outc, CB);
    }
}